// Round 8
// baseline (715.290 us; speedup 1.0000x reference)
//
#include <hip/hip_runtime.h>
#include <hip/hip_bf16.h>
#include <math.h>

#define N_NODES 50000
#define N_EDGES 800000
#define DIM 256
#define MPAD 50176   /* 1568 tiles of 32 rows */
#define LN_EPS 1e-5f
#define SCAN_BLOCKS 196  /* 196*256 = 50176 >= N_NODES */

typedef short bf16x8 __attribute__((ext_vector_type(8)));
typedef float f32x16 __attribute__((ext_vector_type(16)));
typedef unsigned short u16;
typedef u16 u16x8 __attribute__((ext_vector_type(8)));
typedef unsigned int u32;

__device__ __forceinline__ u16 f2bf(float f) {
    union { float f; unsigned u; } v; v.f = f;
    unsigned r = (v.u + 0x7FFFu + ((v.u >> 16) & 1u)) >> 16;
    return (u16)r;
}
__device__ __forceinline__ float bf2f(u16 h) {
    union { unsigned u; float f; } v; v.u = ((unsigned)h) << 16;
    return v.f;
}
// tanh-form gelu via sigmoid: max |err| vs exact ~3e-3, inside tolerance.
__device__ __forceinline__ float gelu_f(float x) {
    float z = x * (1.595769122f + 0.0713548162726f * x * x);
    return x * (1.0f / (1.0f + __expf(-z)));
}

// ---------------- CSR build (known-good round-3/5 chain, unchanged) ---------
__global__ void count_kernel(const int* __restrict__ dst, int* __restrict__ counts) {
    int e = blockIdx.x * 256 + threadIdx.x;
    if (e < N_EDGES) atomicAdd(&counts[dst[e]], 1);
}

__global__ void scan1_kernel(const int* __restrict__ counts, int* __restrict__ offsets,
                             int* __restrict__ bsum) {
    __shared__ int sh[256];
    int t = threadIdx.x;
    int idx = blockIdx.x * 256 + t;
    int v = (idx < N_NODES) ? counts[idx] : 0;
    sh[t] = v;
    __syncthreads();
#pragma unroll
    for (int off = 1; off < 256; off <<= 1) {
        int u = (t >= off) ? sh[t - off] : 0;
        __syncthreads();
        sh[t] += u;
        __syncthreads();
    }
    if (idx < N_NODES) offsets[idx] = sh[t] - v;
    if (t == 255) bsum[blockIdx.x] = sh[255];
}

__global__ void scan2_kernel(const int* __restrict__ bsum, int* __restrict__ bbase) {
    __shared__ int sh[256];
    int t = threadIdx.x;
    int v = (t < SCAN_BLOCKS) ? bsum[t] : 0;
    sh[t] = v;
    __syncthreads();
#pragma unroll
    for (int off = 1; off < 256; off <<= 1) {
        int u = (t >= off) ? sh[t - off] : 0;
        __syncthreads();
        sh[t] += u;
        __syncthreads();
    }
    if (t < SCAN_BLOCKS) bbase[t] = sh[t] - v;
}

__global__ void scan3_kernel(int* __restrict__ offsets, const int* __restrict__ bbase,
                             int* __restrict__ cursor) {
    int idx = blockIdx.x * 256 + threadIdx.x;
    if (idx < N_NODES) {
        int o = offsets[idx] + bbase[blockIdx.x];
        offsets[idx] = o;
        cursor[idx] = o;
    }
    if (idx == 0) offsets[N_NODES] = N_EDGES;
}

__global__ void scatter_kernel(const int* __restrict__ src, const int* __restrict__ dst,
                               const float* __restrict__ w, int* __restrict__ cursor,
                               int2* __restrict__ ep) {
    int e = blockIdx.x * 256 + threadIdx.x;
    if (e < N_EDGES) {
        int d = dst[e];
        int p = atomicAdd(&cursor[d], 1);
        int2 v; v.x = src[e]; v.y = __float_as_int(w[e]);
        ep[p] = v;
    }
}

// ---------------- f32 -> bf16 row conversion (row-major out) ----------------
__global__ void conv_kernel(const float* __restrict__ in, u16* __restrict__ out) {
    int i = blockIdx.x * 256 + threadIdx.x;
    float4 v = ((const float4*)in)[i];
    ushort4 o;
    o.x = f2bf(v.x); o.y = f2bf(v.y); o.z = f2bf(v.z); o.w = f2bf(v.w);
    ((ushort4*)out)[i] = o;
}

// ---------------- weight -> MFMA B-fragment granules, bf16 ----------------
// BF[m][t][kb][lane][j] = bf16(W_m[k][n]), n = t*32+(lane&31),
// k = kb*16+(lane>>5)*8+j -> wave B-frag load = one coalesced 1KB read.
__global__ void convw_kernel(const float* __restrict__ W1, const float* __restrict__ W2,
                             const float* __restrict__ Wp, u16* __restrict__ BF) {
    int idx = blockIdx.x * 256 + threadIdx.x;
    int j = idx & 7;
    int lane = (idx >> 3) & 63;
    int kb = (idx >> 9) & 15;
    int t = (idx >> 13) & 7;
    int m = idx >> 16;
    int n = t * 32 + (lane & 31);
    int k = kb * 16 + (lane >> 5) * 8 + j;
    const float* W = (m == 0) ? W1 : (m == 1) ? W2 : Wp;
    BF[idx] = f2bf(W[k * 256 + n]);
}

// ---------------- col-sliced XCD-affine gather (CSR edges) ------------------
// SINGLE CHANGE vs round 5: replaces spmm_kernel. Grid 12544: block b ->
// (tile = b>>3, slice = b&7). HW round-robins blockIdx over XCDs, so XCD k
// only touches x[:, 32k..32k+32) = 3.2MB -> L2-RESIDENT; per-layer L2-miss
// traffic drops 186MB -> ~78MB (51MB ep re-read + 25.6MB x + misc), and the
// 410MB of gather delivery comes from L2 hits instead of the ~2.9 TB/s
// L2-miss path that has capped every full-row gather at ~64us.
// Wave = 4 groups x 16 lanes; group g takes edges p = p0+g, p0+g+4, ...
// (stride 4, no OOB). Lane = one u32 = 2 bf16 cols. 8 nodes/wave.
// Output: 2KB contiguous slice of the tiled-32 A-fragment granule range ->
// full-line coalesced writes, no amplification.
__global__ __launch_bounds__(256) void cgather_kernel(
        const u16* __restrict__ x, const int* __restrict__ offs,
        const int2* __restrict__ ep, u16* __restrict__ y) {
    __shared__ __align__(16) u16 stg[1024];  // 2KB output slice
    int bid = blockIdx.x;
    int slice = bid & 7;
    int tile = bid >> 3;
    int tid = threadIdx.x;
    int wave = tid >> 6, lane = tid & 63;
    int grp = lane >> 4;       // edge-parallel group 0..3
    int l16 = lane & 15;       // col-pair: local cols 2*l16, 2*l16+1
    const u16* xs = x + slice * 32;

#pragma unroll 1
    for (int i = 0; i < 8; ++i) {
        int node = tile * 32 + wave * 8 + i;
        float a0 = 0.f, a1 = 0.f;
        if (node < N_NODES) {
            if (grp == 0) {  // self row slice
                u32 sv = *(const u32*)(xs + (size_t)node * 256 + l16 * 2);
                a0 = __uint_as_float(sv << 16);
                a1 = __uint_as_float(sv & 0xffff0000u);
            }
            int p1 = offs[node + 1];
#pragma unroll 1
            for (int p = offs[node] + grp; p < p1; p += 4) {
                int2 e = ep[p];
                float w = __int_as_float(e.y);
                u32 v = *(const u32*)(xs + (size_t)e.x * 256 + l16 * 2);
                a0 += w * __uint_as_float(v << 16);
                a1 += w * __uint_as_float(v & 0xffff0000u);
            }
        }
        // reduce the 4 edge-groups (lanes l, l^16, l^32, l^48 hold same cols)
        a0 += __shfl_xor(a0, 16); a0 += __shfl_xor(a0, 32);
        a1 += __shfl_xor(a1, 16); a1 += __shfl_xor(a1, 32);
        if (grp == 0) {
            int m = wave * 8 + i;
            int c = l16 * 2;  // local col (even)
            int gidx = (((c >> 4) * 64) + (((c >> 3) & 1) * 32) + m) * 8 + (c & 7);
            ((u32*)stg)[gidx >> 1] = (u32)f2bf(a0) | ((u32)f2bf(a1) << 16);
        }
    }
    __syncthreads();
    // coalesced 2KB slice write: granules [slice*128, slice*128+128)
    uint2* d2 = (uint2*)(y + (size_t)tile * 8192 + (size_t)slice * 1024);
    d2[tid] = ((const uint2*)stg)[tid];
}

// ---------------- GEMM (v5 barrier-free, LDS-free; known quantity) ----------
// Each wave owns one 32-row tile; A tiled-32 (contiguous 16B/lane frags),
// B = 1KB L2-resident granules (BF layout).
// MODE 0: out = bf16(gelu(LN(A@B+bias))), OUT_TILED: 0=row-major, 1=tiled-32.
// MODE 1: f_out = A@B + bias (f32 row-major, guarded).
template <int MODE, int OUT_TILED>
__global__ __launch_bounds__(256, 2) void gemm_kernel(
        const u16* __restrict__ A, const u16* __restrict__ BF,
        const float* __restrict__ bias, const float* __restrict__ g,
        const float* __restrict__ be, u16* __restrict__ xb_out,
        float* __restrict__ f_out) {
    int tid = threadIdx.x;
    int wave = tid >> 6, lane = tid & 63;
    int l31 = lane & 31, half = lane >> 5;

    int tile = blockIdx.x * 4 + wave;
    const u16* ga = A + (size_t)tile * 8192 + lane * 8;
    const u16* gb = BF + (size_t)lane * 8;
    bf16x8 p = *(const bf16x8*)ga;

    f32x16 acc[8];
#pragma unroll
    for (int t = 0; t < 8; ++t)
#pragma unroll
        for (int r = 0; r < 16; ++r) acc[t][r] = 0.f;

#pragma unroll
    for (int kb = 0; kb < 16; ++kb) {
        bf16x8 a = p;
        if (kb < 15) p = *(const bf16x8*)(ga + (kb + 1) * 512);
#pragma unroll
        for (int t = 0; t < 8; ++t) {
            bf16x8 bf = *(const bf16x8*)(gb + (size_t)(t * 16 + kb) * 512);
            acc[t] = __builtin_amdgcn_mfma_f32_32x32x16_bf16(a, bf, acc[t], 0, 0, 0);
        }
    }

    float bv[8];
#pragma unroll
    for (int t = 0; t < 8; ++t) bv[t] = bias[t * 32 + l31];

    if (MODE == 0) {
        float gv[8], bev[8];
#pragma unroll
        for (int t = 0; t < 8; ++t) {
            int c = t * 32 + l31;
            gv[t] = g[c]; bev[t] = be[c];
        }
#pragma unroll
        for (int r = 0; r < 16; ++r) {
            float s = 0.f, q = 0.f;
#pragma unroll
            for (int t = 0; t < 8; ++t) {
                float v = acc[t][r] + bv[t];
                acc[t][r] = v;
                s += v; q += v * v;
            }
            for (int off = 1; off < 32; off <<= 1) {
                s += __shfl_xor(s, off);
                q += __shfl_xor(q, off);
            }
            float mu = s * (1.0f / 256.0f);
            float var = q * (1.0f / 256.0f) - mu * mu;
            float rs = rsqrtf(var + LN_EPS);
            int m = (r & 3) + 8 * (r >> 2) + 4 * half;
            int row = tile * 32 + m;
#pragma unroll
            for (int t = 0; t < 8; ++t) {
                int c = t * 32 + l31;
                float v = (acc[t][r] - mu) * rs * gv[t] + bev[t];
                u16 ob = f2bf(gelu_f(v));
                if (OUT_TILED) {
                    size_t o = (size_t)tile * 8192 +
                               ((size_t)(c >> 4) * 64 + ((c >> 3) & 1) * 32 + m) * 8 + (c & 7);
                    xb_out[o] = ob;
                } else {
                    xb_out[(size_t)row * 256 + c] = ob;
                }
            }
        }
    } else {
#pragma unroll
        for (int r = 0; r < 16; ++r) {
            int m = (r & 3) + 8 * (r >> 2) + 4 * half;
            int row = tile * 32 + m;
            if (row < N_NODES) {
#pragma unroll
                for (int t = 0; t < 8; ++t) {
                    int c = t * 32 + l31;
                    f_out[(size_t)row * 256 + c] = acc[t][r] + bv[t];
                }
            }
        }
    }
}

extern "C" void kernel_launch(void* const* d_in, const int* in_sizes, int n_in,
                              void* d_out, int out_size, void* d_ws, size_t ws_size,
                              hipStream_t stream) {
    const float* nodef = (const float*)d_in[0];
    const int*   src   = (const int*)d_in[1];
    const int*   dst   = (const int*)d_in[2];
    const float* ew    = (const float*)d_in[3];
    const float* W1 = (const float*)d_in[4];
    const float* b1 = (const float*)d_in[5];
    const float* g1 = (const float*)d_in[6];
    const float* be1 = (const float*)d_in[7];
    const float* W2 = (const float*)d_in[8];
    const float* b2 = (const float*)d_in[9];
    const float* g2 = (const float*)d_in[10];
    const float* be2 = (const float*)d_in[11];
    const float* Wp = (const float*)d_in[12];
    const float* bp = (const float*)d_in[13];
    float* out = (float*)d_out;

    char* ws = (char*)d_ws;
    size_t off = 0;
    auto alloc = [&](size_t bytes) -> void* {
        void* p = ws + off;
        off += (bytes + 255) & ~(size_t)255;
        return p;
    };
    u16*   ybuf    = (u16*)alloc((size_t)MPAD * 256 * 2);  // tiled-32 activations
    u16*   xbuf    = (u16*)alloc((size_t)MPAD * 256 * 2);  // row-major / tiled h2
    u16*   WT      = (u16*)alloc((size_t)3 * 65536 * 2);   // B fragment granules
    int*   counts  = (int*)alloc((size_t)N_NODES * 4);
    int*   offsets = (int*)alloc((size_t)(N_NODES + 1) * 4);
    int*   cursor  = (int*)alloc((size_t)N_NODES * 4);
    int2*  ep      = (int2*)alloc((size_t)N_EDGES * 8);
    int*   bsum    = (int*)alloc((size_t)SCAN_BLOCKS * 4);
    int*   bbase   = (int*)alloc((size_t)SCAN_BLOCKS * 4);

    hipMemsetAsync(counts, 0, (size_t)N_NODES * 4, stream);
    count_kernel<<<(N_EDGES + 255) / 256, 256, 0, stream>>>(dst, counts);
    scan1_kernel<<<SCAN_BLOCKS, 256, 0, stream>>>(counts, offsets, bsum);
    scan2_kernel<<<1, 256, 0, stream>>>(bsum, bbase);
    scan3_kernel<<<SCAN_BLOCKS, 256, 0, stream>>>(offsets, bbase, cursor);
    scatter_kernel<<<(N_EDGES + 255) / 256, 256, 0, stream>>>(src, dst, ew, cursor, ep);
    conv_kernel<<<N_NODES * 64 / 256, 256, 0, stream>>>(nodef, xbuf);
    convw_kernel<<<768, 256, 0, stream>>>(W1, W2, Wp, WT);

    const int CG = (MPAD / 32) * 8;  // 12544 col-sliced gather blocks
    const int GB = MPAD / 128;       // 392 gemm blocks (4 waves x 1 tile)
    // layer 1: col-gather xbuf(row) -> ybuf(tiled); gemm -> xbuf(row-major)
    cgather_kernel<<<CG, 256, 0, stream>>>(xbuf, offsets, ep, ybuf);
    gemm_kernel<0, 0><<<GB, 256, 0, stream>>>(ybuf, WT, b1, g1, be1, xbuf, nullptr);
    // layer 2: col-gather xbuf(row) -> ybuf(tiled); gemm -> xbuf(tiled-32)
    cgather_kernel<<<CG, 256, 0, stream>>>(xbuf, offsets, ep, ybuf);
    gemm_kernel<0, 1><<<GB, 256, 0, stream>>>(ybuf, WT + 65536, b2, g2, be2, xbuf, nullptr);
    // projection: tiled-32 A -> f32 row-major out
    gemm_kernel<1, 0><<<GB, 256, 0, stream>>>(xbuf, WT + 2 * 65536, bp, nullptr, nullptr, nullptr, out);
}

// Round 9
// 434.619 us; speedup vs baseline: 1.6458x; 1.6458x over previous
//
#include <hip/hip_runtime.h>
#include <hip/hip_bf16.h>
#include <math.h>

#define N_NODES 50000
#define N_EDGES 800000
#define DIM 256
#define MPAD 50176   /* 1568 tiles of 32 rows */
#define LN_EPS 1e-5f
#define SCAN_BLOCKS 196  /* 196*256 = 50176 >= N_NODES */

typedef short bf16x8 __attribute__((ext_vector_type(8)));
typedef float f32x16 __attribute__((ext_vector_type(16)));
typedef unsigned short u16;
typedef u16 u16x8 __attribute__((ext_vector_type(8)));
typedef unsigned int u32;

__device__ __forceinline__ u16 f2bf(float f) {
    union { float f; unsigned u; } v; v.f = f;
    unsigned r = (v.u + 0x7FFFu + ((v.u >> 16) & 1u)) >> 16;
    return (u16)r;
}
__device__ __forceinline__ float bf2f(u16 h) {
    union { unsigned u; float f; } v; v.u = ((unsigned)h) << 16;
    return v.f;
}
// tanh-form gelu via sigmoid: max |err| vs exact ~3e-3, inside tolerance.
__device__ __forceinline__ float gelu_f(float x) {
    float z = x * (1.595769122f + 0.0713548162726f * x * x);
    return x * (1.0f / (1.0f + __expf(-z)));
}

// ---------------- init: count + conv + convw in ONE dispatch ----------------
// blocks [0,3125): edge-count atomics (counts must be pre-zeroed by memset)
// blocks [3125,15625): f32->bf16 node features (row-major)
// blocks [15625,16393): weights -> MFMA B-fragment granules:
//   BF[m][t][kb][lane][j] = bf16(W_m[k][n]), n = t*32+(lane&31),
//   k = kb*16+(lane>>5)*8+j -> wave B-frag load = one coalesced 1KB read.
__global__ void init_kernel(const int* __restrict__ dst, int* __restrict__ counts,
                            const float* __restrict__ nodef, u16* __restrict__ xb,
                            const float* __restrict__ W1, const float* __restrict__ W2,
                            const float* __restrict__ Wp, u16* __restrict__ BF) {
    int b = blockIdx.x;
    int tid = threadIdx.x;
    if (b < 3125) {
        int e = b * 256 + tid;
        if (e < N_EDGES) atomicAdd(&counts[dst[e]], 1);
    } else if (b < 15625) {
        int i = (b - 3125) * 256 + tid;
        float4 v = ((const float4*)nodef)[i];
        ushort4 o;
        o.x = f2bf(v.x); o.y = f2bf(v.y); o.z = f2bf(v.z); o.w = f2bf(v.w);
        ((ushort4*)xb)[i] = o;
    } else {
        int idx = (b - 15625) * 256 + tid;
        int j = idx & 7;
        int lane = (idx >> 3) & 63;
        int kb = (idx >> 9) & 15;
        int t = (idx >> 13) & 7;
        int m = idx >> 16;
        int n = t * 32 + (lane & 31);
        int k = kb * 16 + (lane >> 5) * 8 + j;
        const float* W = (m == 0) ? W1 : (m == 1) ? W2 : Wp;
        BF[idx] = f2bf(W[k * 256 + n]);
    }
}

__global__ void scan1_kernel(const int* __restrict__ counts, int* __restrict__ offsets,
                             int* __restrict__ bsum) {
    __shared__ int sh[256];
    int t = threadIdx.x;
    int idx = blockIdx.x * 256 + t;
    int v = (idx < N_NODES) ? counts[idx] : 0;
    sh[t] = v;
    __syncthreads();
#pragma unroll
    for (int off = 1; off < 256; off <<= 1) {
        int u = (t >= off) ? sh[t - off] : 0;
        __syncthreads();
        sh[t] += u;
        __syncthreads();
    }
    if (idx < N_NODES) offsets[idx] = sh[t] - v;
    if (t == 255) bsum[blockIdx.x] = sh[255];
}

// scan2+scan3 merged: every block redundantly scans the 196-entry bsum in LDS
// (trivial), then applies its own block base. Deletes one serial dispatch.
__global__ void scan23_kernel(const int* __restrict__ bsum, int* __restrict__ offsets,
                              int* __restrict__ cursor) {
    __shared__ int sh[256];
    int t = threadIdx.x;
    int v = (t < SCAN_BLOCKS) ? bsum[t] : 0;
    sh[t] = v;
    __syncthreads();
#pragma unroll
    for (int off = 1; off < 256; off <<= 1) {
        int u = (t >= off) ? sh[t - off] : 0;
        __syncthreads();
        sh[t] += u;
        __syncthreads();
    }
    int b = blockIdx.x;
    int base = (b == 0) ? 0 : sh[b - 1];   // exclusive prefix of bsum up to b
    __syncthreads();
    int idx = b * 256 + t;
    if (idx < N_NODES) {
        int o = offsets[idx] + base;
        offsets[idx] = o;
        cursor[idx] = o;
    }
    if (idx == 0) offsets[N_NODES] = N_EDGES;
}

__global__ void scatter_kernel(const int* __restrict__ src, const int* __restrict__ dst,
                               const float* __restrict__ w, int* __restrict__ cursor,
                               int2* __restrict__ ep) {
    int e = blockIdx.x * 256 + threadIdx.x;
    if (e < N_EDGES) {
        int d = dst[e];
        int p = atomicAdd(&cursor[d], 1);
        int2 v; v.x = src[e]; v.y = __float_as_int(w[e]);
        ep[p] = v;
    }
}

// ---------------- FUSED layer: gather + GEMM + LN + gelu -------------------
// BYTE-IDENTICAL to the round-6 version (best measured: 107us/layer).
// Block = one 32-row tile (1568 blocks). Phase 1: spmm gather -> LDS tile.
// Phase 2: 4 waves x 2 col-tiles of 32x32x16 MFMA; A-frags = ds_read_b128,
// B = 1KB L2-resident granules (BF layout). Phase 3: cross-wave LN + gelu.
// OUT_TILED=0: row-major bf16 out; OUT_TILED=1: tiled-32 A-fragment out.
template <int OUT_TILED>
__global__ __launch_bounds__(256, 4) void fused_kernel(
        const u16* __restrict__ x, const int* __restrict__ offs,
        const int2* __restrict__ ep, const u16* __restrict__ BF,
        const float* __restrict__ bias, const float* __restrict__ g,
        const float* __restrict__ be, u16* __restrict__ out) {
    __shared__ u16 tile[32 * 264];   // 16.9 KB, padded rows
    __shared__ float red[32][8];     // per-row (s,q) partials per wave
    __shared__ float mur[32], rsr[32];
    int tid = threadIdx.x;
    int wave = tid >> 6;
    int lane = tid & 63;
    int l31 = lane & 31, half = lane >> 5;
    int node0 = blockIdx.x * 32 + wave * 8;

    // ---- phase 1: gather ----
    const ushort4* xv = (const ushort4*)x;
#pragma unroll 1
    for (int i = 0; i < 8; ++i) {
        int node = node0 + i;
        float a0 = 0, a1 = 0, a2 = 0, a3 = 0;
        float b0 = 0, b1 = 0, b2 = 0, b3 = 0;
        float c0 = 0, c1 = 0, c2 = 0, c3 = 0;
        float d0 = 0, d1 = 0, d2 = 0, d3 = 0;
        if (node < N_NODES) {
            ushort4 v = xv[(size_t)node * 64 + lane];
            a0 = bf2f(v.x); a1 = bf2f(v.y); a2 = bf2f(v.z); a3 = bf2f(v.w);
            int p = offs[node];
            int p1 = offs[node + 1];
            for (; p + 4 <= p1; p += 4) {
                int2 e0 = ep[p],     e1 = ep[p + 1];
                int2 e2 = ep[p + 2], e3 = ep[p + 3];
                int s0 = e0.x; float w0 = __int_as_float(e0.y);
                int s1 = e1.x; float w1 = __int_as_float(e1.y);
                int s2 = e2.x; float w2 = __int_as_float(e2.y);
                int s3 = e3.x; float w3 = __int_as_float(e3.y);
                ushort4 v0 = xv[(size_t)s0 * 64 + lane];
                ushort4 v1 = xv[(size_t)s1 * 64 + lane];
                ushort4 v2 = xv[(size_t)s2 * 64 + lane];
                ushort4 v3 = xv[(size_t)s3 * 64 + lane];
                a0 += w0 * bf2f(v0.x); a1 += w0 * bf2f(v0.y); a2 += w0 * bf2f(v0.z); a3 += w0 * bf2f(v0.w);
                b0 += w1 * bf2f(v1.x); b1 += w1 * bf2f(v1.y); b2 += w1 * bf2f(v1.z); b3 += w1 * bf2f(v1.w);
                c0 += w2 * bf2f(v2.x); c1 += w2 * bf2f(v2.y); c2 += w2 * bf2f(v2.z); c3 += w2 * bf2f(v2.w);
                d0 += w3 * bf2f(v3.x); d1 += w3 * bf2f(v3.y); d2 += w3 * bf2f(v3.z); d3 += w3 * bf2f(v3.w);
            }
            for (; p < p1; ++p) {
                int2 e = ep[p];
                int s = e.x;
                float w = __int_as_float(e.y);
                ushort4 vv = xv[(size_t)s * 64 + lane];
                a0 += w * bf2f(vv.x); a1 += w * bf2f(vv.y); a2 += w * bf2f(vv.z); a3 += w * bf2f(vv.w);
            }
            a0 += b0 + c0 + d0; a1 += b1 + c1 + d1;
            a2 += b2 + c2 + d2; a3 += b3 + c3 + d3;
        }
        ushort4 o;
        o.x = f2bf(a0); o.y = f2bf(a1); o.z = f2bf(a2); o.w = f2bf(a3);
        ((ushort4*)&tile[(wave * 8 + i) * 264])[lane] = o;
    }
    __syncthreads();

    // ---- phase 2: GEMM. wave w owns col-tiles t0=2w, t1=2w+1 ----
    int t0 = wave * 2, t1 = wave * 2 + 1;
    const u16* gb = BF + (size_t)lane * 8;
    f32x16 acc0, acc1;
#pragma unroll
    for (int r = 0; r < 16; ++r) { acc0[r] = 0.f; acc1[r] = 0.f; }
#pragma unroll
    for (int kb = 0; kb < 16; ++kb) {
        bf16x8 a = *(const bf16x8*)&tile[l31 * 264 + kb * 16 + half * 8];
        bf16x8 bf0 = *(const bf16x8*)(gb + (size_t)(t0 * 16 + kb) * 512);
        bf16x8 bf1 = *(const bf16x8*)(gb + (size_t)(t1 * 16 + kb) * 512);
        acc0 = __builtin_amdgcn_mfma_f32_32x32x16_bf16(a, bf0, acc0, 0, 0, 0);
        acc1 = __builtin_amdgcn_mfma_f32_32x32x16_bf16(a, bf1, acc1, 0, 0, 0);
    }

    // ---- phase 3: bias + cross-wave LN + gelu ----
    float bv0 = bias[t0 * 32 + l31], bv1 = bias[t1 * 32 + l31];
    float gv0 = g[t0 * 32 + l31],    gv1 = g[t1 * 32 + l31];
    float ev0 = be[t0 * 32 + l31],   ev1 = be[t1 * 32 + l31];
#pragma unroll
    for (int r = 0; r < 16; ++r) {
        float v0 = acc0[r] + bv0, v1 = acc1[r] + bv1;
        acc0[r] = v0; acc1[r] = v1;
        float s = v0 + v1, q = v0 * v0 + v1 * v1;
#pragma unroll
        for (int off = 1; off < 32; off <<= 1) {
            s += __shfl_xor(s, off);
            q += __shfl_xor(q, off);
        }
        if (l31 == 0) {
            int rw = (r & 3) + 8 * (r >> 2) + 4 * half;  // row in tile
            red[rw][wave * 2] = s;
            red[rw][wave * 2 + 1] = q;
        }
    }
    __syncthreads();
    if (tid < 32) {
        float s = red[tid][0] + red[tid][2] + red[tid][4] + red[tid][6];
        float q = red[tid][1] + red[tid][3] + red[tid][5] + red[tid][7];
        float mu = s * (1.0f / 256.0f);
        float var = q * (1.0f / 256.0f) - mu * mu;
        mur[tid] = mu;
        rsr[tid] = rsqrtf(var + LN_EPS);
    }
    __syncthreads();
#pragma unroll
    for (int r = 0; r < 16; ++r) {
        int rw = (r & 3) + 8 * (r >> 2) + 4 * half;
        float mu = mur[rw], rs = rsr[rw];
        float v0 = (acc0[r] - mu) * rs * gv0 + ev0;
        float v1 = (acc1[r] - mu) * rs * gv1 + ev1;
        u16 o0 = f2bf(gelu_f(v0));
        u16 o1 = f2bf(gelu_f(v1));
        int c0 = t0 * 32 + l31, c1 = t1 * 32 + l31;
        if (OUT_TILED) {
            size_t base = (size_t)blockIdx.x * 8192;
            out[base + ((size_t)(c0 >> 4) * 64 + ((c0 >> 3) & 1) * 32 + rw) * 8 + (c0 & 7)] = o0;
            out[base + ((size_t)(c1 >> 4) * 64 + ((c1 >> 3) & 1) * 32 + rw) * 8 + (c1 & 7)] = o1;
        } else {
            size_t rg = (size_t)(blockIdx.x * 32 + rw) * 256;
            out[rg + c0] = o0;
            out[rg + c1] = o1;
        }
    }
}

// ---------------- projection GEMM (v5 barrier-free; unchanged) --------------
__global__ __launch_bounds__(256, 2) void proj_kernel(
        const u16* __restrict__ A, const u16* __restrict__ BF,
        const float* __restrict__ bias, float* __restrict__ f_out) {
    int tid = threadIdx.x;
    int wave = tid >> 6, lane = tid & 63;
    int l31 = lane & 31, half = lane >> 5;

    int tile = blockIdx.x * 4 + wave;
    const u16* ga = A + (size_t)tile * 8192 + lane * 8;
    const u16* gb = BF + (size_t)lane * 8;
    bf16x8 p = *(const bf16x8*)ga;

    f32x16 acc[8];
#pragma unroll
    for (int t = 0; t < 8; ++t)
#pragma unroll
        for (int r = 0; r < 16; ++r) acc[t][r] = 0.f;

#pragma unroll
    for (int kb = 0; kb < 16; ++kb) {
        bf16x8 a = p;
        if (kb < 15) p = *(const bf16x8*)(ga + (kb + 1) * 512);
#pragma unroll
        for (int t = 0; t < 8; ++t) {
            bf16x8 bf = *(const bf16x8*)(gb + (size_t)(t * 16 + kb) * 512);
            acc[t] = __builtin_amdgcn_mfma_f32_32x32x16_bf16(a, bf, acc[t], 0, 0, 0);
        }
    }

    float bv[8];
#pragma unroll
    for (int t = 0; t < 8; ++t) bv[t] = bias[t * 32 + l31];

#pragma unroll
    for (int r = 0; r < 16; ++r) {
        int m = (r & 3) + 8 * (r >> 2) + 4 * half;
        int row = tile * 32 + m;
        if (row < N_NODES) {
#pragma unroll
            for (int t = 0; t < 8; ++t) {
                int c = t * 32 + l31;
                f_out[(size_t)row * 256 + c] = acc[t][r] + bv[t];
            }
        }
    }
}

extern "C" void kernel_launch(void* const* d_in, const int* in_sizes, int n_in,
                              void* d_out, int out_size, void* d_ws, size_t ws_size,
                              hipStream_t stream) {
    const float* nodef = (const float*)d_in[0];
    const int*   src   = (const int*)d_in[1];
    const int*   dst   = (const int*)d_in[2];
    const float* ew    = (const float*)d_in[3];
    const float* W1 = (const float*)d_in[4];
    const float* b1 = (const float*)d_in[5];
    const float* g1 = (const float*)d_in[6];
    const float* be1 = (const float*)d_in[7];
    const float* W2 = (const float*)d_in[8];
    const float* b2 = (const float*)d_in[9];
    const float* g2 = (const float*)d_in[10];
    const float* be2 = (const float*)d_in[11];
    const float* Wp = (const float*)d_in[12];
    const float* bp = (const float*)d_in[13];
    float* out = (float*)d_out;

    char* ws = (char*)d_ws;
    size_t off = 0;
    auto alloc = [&](size_t bytes) -> void* {
        void* p = ws + off;
        off += (bytes + 255) & ~(size_t)255;
        return p;
    };
    u16*   ybuf    = (u16*)alloc((size_t)MPAD * 256 * 2);  // h1 row-major
    u16*   xbuf    = (u16*)alloc((size_t)MPAD * 256 * 2);  // conv out / h2 tiled
    u16*   WT      = (u16*)alloc((size_t)3 * 65536 * 2);   // B fragment granules
    int*   counts  = (int*)alloc((size_t)N_NODES * 4);
    int*   offsets = (int*)alloc((size_t)(N_NODES + 1) * 4);
    int*   cursor  = (int*)alloc((size_t)N_NODES * 4);
    int2*  ep      = (int2*)alloc((size_t)N_EDGES * 8);
    int*   bsum    = (int*)alloc((size_t)SCAN_BLOCKS * 4);

    // 8 dispatches (was 11): count/conv/convw merged; scan2+scan3 merged.
    hipMemsetAsync(counts, 0, (size_t)N_NODES * 4, stream);
    init_kernel<<<16393, 256, 0, stream>>>(dst, counts, nodef, xbuf, W1, W2, Wp, WT);
    scan1_kernel<<<SCAN_BLOCKS, 256, 0, stream>>>(counts, offsets, bsum);
    scan23_kernel<<<SCAN_BLOCKS, 256, 0, stream>>>(bsum, offsets, cursor);
    scatter_kernel<<<(N_EDGES + 255) / 256, 256, 0, stream>>>(src, dst, ew, cursor, ep);

    const int SB = MPAD / 32;    // 1568 fused tile-blocks
    const int GB = MPAD / 128;   // 392 proj blocks (4 waves x 1 tile)
    // layer 1: gather+gemm+LN+gelu, xbuf(row) -> ybuf(row-major)
    fused_kernel<0><<<SB, 256, 0, stream>>>(xbuf, offsets, ep, WT, b1, g1, be1, ybuf);
    // layer 2: gather+gemm+LN+gelu, ybuf(row) -> xbuf(tiled-32)
    fused_kernel<1><<<SB, 256, 0, stream>>>(ybuf, offsets, ep, WT + 65536, b2, g2, be2, xbuf);
    // projection: tiled-32 A -> f32 row-major out
    proj_kernel<<<GB, 256, 0, stream>>>(xbuf, WT + 2 * 65536, bp, out);
}

// Round 10
// 416.585 us; speedup vs baseline: 1.7170x; 1.0433x over previous
//
#include <hip/hip_runtime.h>
#include <hip/hip_bf16.h>
#include <math.h>

#define N_NODES 50000
#define N_EDGES 800000
#define DIM 256
#define MPAD 50176   /* 1568 tiles of 32 rows */
#define LN_EPS 1e-5f
#define SCAN_BLOCKS 196  /* 196*256 = 50176 >= N_NODES */

typedef short bf16x8 __attribute__((ext_vector_type(8)));
typedef float f32x16 __attribute__((ext_vector_type(16)));
typedef unsigned short u16;
typedef u16 u16x8 __attribute__((ext_vector_type(8)));
typedef unsigned int u32;

__device__ __forceinline__ u16 f2bf(float f) {
    union { float f; unsigned u; } v; v.f = f;
    unsigned r = (v.u + 0x7FFFu + ((v.u >> 16) & 1u)) >> 16;
    return (u16)r;
}
__device__ __forceinline__ float bf2f(u16 h) {
    union { unsigned u; float f; } v; v.u = ((unsigned)h) << 16;
    return v.f;
}
// tanh-form gelu via sigmoid: max |err| vs exact ~3e-3, inside tolerance.
__device__ __forceinline__ float gelu_f(float x) {
    float z = x * (1.595769122f + 0.0713548162726f * x * x);
    return x * (1.0f / (1.0f + __expf(-z)));
}

// ---------------- init: count + conv + convw in ONE dispatch ----------------
__global__ void init_kernel(const int* __restrict__ dst, int* __restrict__ counts,
                            const float* __restrict__ nodef, u16* __restrict__ xb,
                            const float* __restrict__ W1, const float* __restrict__ W2,
                            const float* __restrict__ Wp, u16* __restrict__ BF) {
    int b = blockIdx.x;
    int tid = threadIdx.x;
    if (b < 3125) {
        int e = b * 256 + tid;
        if (e < N_EDGES) atomicAdd(&counts[dst[e]], 1);
    } else if (b < 15625) {
        int i = (b - 3125) * 256 + tid;
        float4 v = ((const float4*)nodef)[i];
        ushort4 o;
        o.x = f2bf(v.x); o.y = f2bf(v.y); o.z = f2bf(v.z); o.w = f2bf(v.w);
        ((ushort4*)xb)[i] = o;
    } else {
        int idx = (b - 15625) * 256 + tid;
        int j = idx & 7;
        int lane = (idx >> 3) & 63;
        int kb = (idx >> 9) & 15;
        int t = (idx >> 13) & 7;
        int m = idx >> 16;
        int n = t * 32 + (lane & 31);
        int k = kb * 16 + (lane >> 5) * 8 + j;
        const float* W = (m == 0) ? W1 : (m == 1) ? W2 : Wp;
        BF[idx] = f2bf(W[k * 256 + n]);
    }
}

__global__ void scan1_kernel(const int* __restrict__ counts, int* __restrict__ offsets,
                             int* __restrict__ bsum) {
    __shared__ int sh[256];
    int t = threadIdx.x;
    int idx = blockIdx.x * 256 + t;
    int v = (idx < N_NODES) ? counts[idx] : 0;
    sh[t] = v;
    __syncthreads();
#pragma unroll
    for (int off = 1; off < 256; off <<= 1) {
        int u = (t >= off) ? sh[t - off] : 0;
        __syncthreads();
        sh[t] += u;
        __syncthreads();
    }
    if (idx < N_NODES) offsets[idx] = sh[t] - v;
    if (t == 255) bsum[blockIdx.x] = sh[255];
}

// scan2+scan3 merged: every block redundantly scans the 196-entry bsum in LDS.
__global__ void scan23_kernel(const int* __restrict__ bsum, int* __restrict__ offsets,
                              int* __restrict__ cursor) {
    __shared__ int sh[256];
    int t = threadIdx.x;
    int v = (t < SCAN_BLOCKS) ? bsum[t] : 0;
    sh[t] = v;
    __syncthreads();
#pragma unroll
    for (int off = 1; off < 256; off <<= 1) {
        int u = (t >= off) ? sh[t - off] : 0;
        __syncthreads();
        sh[t] += u;
        __syncthreads();
    }
    int b = blockIdx.x;
    int base = (b == 0) ? 0 : sh[b - 1];
    __syncthreads();
    int idx = b * 256 + t;
    if (idx < N_NODES) {
        int o = offsets[idx] + base;
        offsets[idx] = o;
        cursor[idx] = o;
    }
    if (idx == 0) offsets[N_NODES] = N_EDGES;
}

__global__ void scatter_kernel(const int* __restrict__ src, const int* __restrict__ dst,
                               const float* __restrict__ w, int* __restrict__ cursor,
                               int2* __restrict__ ep) {
    int e = blockIdx.x * 256 + threadIdx.x;
    if (e < N_EDGES) {
        int d = dst[e];
        int p = atomicAdd(&cursor[d], 1);
        int2 v; v.x = src[e]; v.y = __float_as_int(w[e]);
        ep[p] = v;
    }
}

// ---------------- FUSED layer: gather + GEMM + LN + gelu -------------------
// Identical to round-9 EXCEPT phase 1: deep-ILP gather. Old loop had max 4
// feature rows in flight (two-level dependent chain: ep load ~200cy -> row
// load ~600-900cy -> FMA). New: branch-free 16-edge chunks — 16 wave-uniform
// 8B descriptor loads, then 16 independent 512B row loads in flight, then
// 64 FMAs. Masked tail edges read row 0 (L1-hot) with weight 0. This is the
// latency-vs-fabric discriminating experiment: fabric-bound => no change;
// latency-bound => phase 1 compresses.
template <int OUT_TILED>
__global__ __launch_bounds__(256, 4) void fused_kernel(
        const u16* __restrict__ x, const int* __restrict__ offs,
        const int2* __restrict__ ep, const u16* __restrict__ BF,
        const float* __restrict__ bias, const float* __restrict__ g,
        const float* __restrict__ be, u16* __restrict__ out) {
    __shared__ u16 tile[32 * 264];   // 16.9 KB, padded rows
    __shared__ float red[32][8];     // per-row (s,q) partials per wave
    __shared__ float mur[32], rsr[32];
    int tid = threadIdx.x;
    int wave = tid >> 6;
    int lane = tid & 63;
    int l31 = lane & 31, half = lane >> 5;
    int node0 = blockIdx.x * 32 + wave * 8;

    // ---- phase 1: deep-ILP gather ----
    const ushort4* xv = (const ushort4*)x;
#pragma unroll 1
    for (int i = 0; i < 8; ++i) {
        int node = node0 + i;
        float a0 = 0, a1 = 0, a2 = 0, a3 = 0;
        if (node < N_NODES) {
            ushort4 v = xv[(size_t)node * 64 + lane];
            a0 = bf2f(v.x); a1 = bf2f(v.y); a2 = bf2f(v.z); a3 = bf2f(v.w);
            int p = offs[node];
            int p1 = offs[node + 1];
#pragma unroll 1
            for (; p < p1; p += 16) {
                int sj[16]; float wj[16];
#pragma unroll
                for (int j = 0; j < 16; ++j) {
                    int2 e = ep[p + j];        // wave-uniform 8B (ep padded +16)
                    bool ok = (p + j) < p1;
                    sj[j] = ok ? e.x : 0;
                    wj[j] = ok ? __int_as_float(e.y) : 0.f;
                }
                ushort4 vv[16];
#pragma unroll
                for (int j = 0; j < 16; ++j)
                    vv[j] = xv[(size_t)sj[j] * 64 + lane];   // 16 rows in flight
#pragma unroll
                for (int j = 0; j < 16; ++j) {
                    a0 += wj[j] * bf2f(vv[j].x);
                    a1 += wj[j] * bf2f(vv[j].y);
                    a2 += wj[j] * bf2f(vv[j].z);
                    a3 += wj[j] * bf2f(vv[j].w);
                }
            }
        }
        ushort4 o;
        o.x = f2bf(a0); o.y = f2bf(a1); o.z = f2bf(a2); o.w = f2bf(a3);
        ((ushort4*)&tile[(wave * 8 + i) * 264])[lane] = o;
    }
    __syncthreads();

    // ---- phase 2: GEMM. wave w owns col-tiles t0=2w, t1=2w+1 ----
    int t0 = wave * 2, t1 = wave * 2 + 1;
    const u16* gb = BF + (size_t)lane * 8;
    f32x16 acc0, acc1;
#pragma unroll
    for (int r = 0; r < 16; ++r) { acc0[r] = 0.f; acc1[r] = 0.f; }
#pragma unroll
    for (int kb = 0; kb < 16; ++kb) {
        bf16x8 a = *(const bf16x8*)&tile[l31 * 264 + kb * 16 + half * 8];
        bf16x8 bf0 = *(const bf16x8*)(gb + (size_t)(t0 * 16 + kb) * 512);
        bf16x8 bf1 = *(const bf16x8*)(gb + (size_t)(t1 * 16 + kb) * 512);
        acc0 = __builtin_amdgcn_mfma_f32_32x32x16_bf16(a, bf0, acc0, 0, 0, 0);
        acc1 = __builtin_amdgcn_mfma_f32_32x32x16_bf16(a, bf1, acc1, 0, 0, 0);
    }

    // ---- phase 3: bias + cross-wave LN + gelu ----
    float bv0 = bias[t0 * 32 + l31], bv1 = bias[t1 * 32 + l31];
    float gv0 = g[t0 * 32 + l31],    gv1 = g[t1 * 32 + l31];
    float ev0 = be[t0 * 32 + l31],   ev1 = be[t1 * 32 + l31];
#pragma unroll
    for (int r = 0; r < 16; ++r) {
        float v0 = acc0[r] + bv0, v1 = acc1[r] + bv1;
        acc0[r] = v0; acc1[r] = v1;
        float s = v0 + v1, q = v0 * v0 + v1 * v1;
#pragma unroll
        for (int off = 1; off < 32; off <<= 1) {
            s += __shfl_xor(s, off);
            q += __shfl_xor(q, off);
        }
        if (l31 == 0) {
            int rw = (r & 3) + 8 * (r >> 2) + 4 * half;  // row in tile
            red[rw][wave * 2] = s;
            red[rw][wave * 2 + 1] = q;
        }
    }
    __syncthreads();
    if (tid < 32) {
        float s = red[tid][0] + red[tid][2] + red[tid][4] + red[tid][6];
        float q = red[tid][1] + red[tid][3] + red[tid][5] + red[tid][7];
        float mu = s * (1.0f / 256.0f);
        float var = q * (1.0f / 256.0f) - mu * mu;
        mur[tid] = mu;
        rsr[tid] = rsqrtf(var + LN_EPS);
    }
    __syncthreads();
#pragma unroll
    for (int r = 0; r < 16; ++r) {
        int rw = (r & 3) + 8 * (r >> 2) + 4 * half;
        float mu = mur[rw], rs = rsr[rw];
        float v0 = (acc0[r] - mu) * rs * gv0 + ev0;
        float v1 = (acc1[r] - mu) * rs * gv1 + ev1;
        u16 o0 = f2bf(gelu_f(v0));
        u16 o1 = f2bf(gelu_f(v1));
        int c0 = t0 * 32 + l31, c1 = t1 * 32 + l31;
        if (OUT_TILED) {
            size_t base = (size_t)blockIdx.x * 8192;
            out[base + ((size_t)(c0 >> 4) * 64 + ((c0 >> 3) & 1) * 32 + rw) * 8 + (c0 & 7)] = o0;
            out[base + ((size_t)(c1 >> 4) * 64 + ((c1 >> 3) & 1) * 32 + rw) * 8 + (c1 & 7)] = o1;
        } else {
            size_t rg = (size_t)(blockIdx.x * 32 + rw) * 256;
            out[rg + c0] = o0;
            out[rg + c1] = o1;
        }
    }
}

// ---------------- projection GEMM (v5 barrier-free; unchanged) --------------
__global__ __launch_bounds__(256, 2) void proj_kernel(
        const u16* __restrict__ A, const u16* __restrict__ BF,
        const float* __restrict__ bias, float* __restrict__ f_out) {
    int tid = threadIdx.x;
    int wave = tid >> 6, lane = tid & 63;
    int l31 = lane & 31, half = lane >> 5;

    int tile = blockIdx.x * 4 + wave;
    const u16* ga = A + (size_t)tile * 8192 + lane * 8;
    const u16* gb = BF + (size_t)lane * 8;
    bf16x8 p = *(const bf16x8*)ga;

    f32x16 acc[8];
#pragma unroll
    for (int t = 0; t < 8; ++t)
#pragma unroll
        for (int r = 0; r < 16; ++r) acc[t][r] = 0.f;

#pragma unroll
    for (int kb = 0; kb < 16; ++kb) {
        bf16x8 a = p;
        if (kb < 15) p = *(const bf16x8*)(ga + (kb + 1) * 512);
#pragma unroll
        for (int t = 0; t < 8; ++t) {
            bf16x8 bf = *(const bf16x8*)(gb + (size_t)(t * 16 + kb) * 512);
            acc[t] = __builtin_amdgcn_mfma_f32_32x32x16_bf16(a, bf, acc[t], 0, 0, 0);
        }
    }

    float bv[8];
#pragma unroll
    for (int t = 0; t < 8; ++t) bv[t] = bias[t * 32 + l31];

#pragma unroll
    for (int r = 0; r < 16; ++r) {
        int m = (r & 3) + 8 * (r >> 2) + 4 * half;
        int row = tile * 32 + m;
        if (row < N_NODES) {
#pragma unroll
            for (int t = 0; t < 8; ++t) {
                int c = t * 32 + l31;
                f_out[(size_t)row * 256 + c] = acc[t][r] + bv[t];
            }
        }
    }
}

extern "C" void kernel_launch(void* const* d_in, const int* in_sizes, int n_in,
                              void* d_out, int out_size, void* d_ws, size_t ws_size,
                              hipStream_t stream) {
    const float* nodef = (const float*)d_in[0];
    const int*   src   = (const int*)d_in[1];
    const int*   dst   = (const int*)d_in[2];
    const float* ew    = (const float*)d_in[3];
    const float* W1 = (const float*)d_in[4];
    const float* b1 = (const float*)d_in[5];
    const float* g1 = (const float*)d_in[6];
    const float* be1 = (const float*)d_in[7];
    const float* W2 = (const float*)d_in[8];
    const float* b2 = (const float*)d_in[9];
    const float* g2 = (const float*)d_in[10];
    const float* be2 = (const float*)d_in[11];
    const float* Wp = (const float*)d_in[12];
    const float* bp = (const float*)d_in[13];
    float* out = (float*)d_out;

    char* ws = (char*)d_ws;
    size_t off = 0;
    auto alloc = [&](size_t bytes) -> void* {
        void* p = ws + off;
        off += (bytes + 255) & ~(size_t)255;
        return p;
    };
    u16*   ybuf    = (u16*)alloc((size_t)MPAD * 256 * 2);  // h1 row-major
    u16*   xbuf    = (u16*)alloc((size_t)MPAD * 256 * 2);  // conv out / h2 tiled
    u16*   WT      = (u16*)alloc((size_t)3 * 65536 * 2);   // B fragment granules
    int*   counts  = (int*)alloc((size_t)N_NODES * 4);
    int*   offsets = (int*)alloc((size_t)(N_NODES + 1) * 4);
    int*   cursor  = (int*)alloc((size_t)N_NODES * 4);
    int2*  ep      = (int2*)alloc((size_t)(N_EDGES + 16) * 8);  // +16: chunk pad
    int*   bsum    = (int*)alloc((size_t)SCAN_BLOCKS * 4);

    // 8 dispatches: memset, init, scan1, scan23, scatter, fused x2, proj.
    hipMemsetAsync(counts, 0, (size_t)N_NODES * 4, stream);
    init_kernel<<<16393, 256, 0, stream>>>(dst, counts, nodef, xbuf, W1, W2, Wp, WT);
    scan1_kernel<<<SCAN_BLOCKS, 256, 0, stream>>>(counts, offsets, bsum);
    scan23_kernel<<<SCAN_BLOCKS, 256, 0, stream>>>(bsum, offsets, cursor);
    scatter_kernel<<<(N_EDGES + 255) / 256, 256, 0, stream>>>(src, dst, ew, cursor, ep);

    const int SB = MPAD / 32;    // 1568 fused tile-blocks
    const int GB = MPAD / 128;   // 392 proj blocks (4 waves x 1 tile)
    // layer 1: gather+gemm+LN+gelu, xbuf(row) -> ybuf(row-major)
    fused_kernel<0><<<SB, 256, 0, stream>>>(xbuf, offsets, ep, WT, b1, g1, be1, ybuf);
    // layer 2: gather+gemm+LN+gelu, ybuf(row) -> xbuf(tiled-32)
    fused_kernel<1><<<SB, 256, 0, stream>>>(ybuf, offsets, ep, WT + 65536, b2, g2, be2, xbuf);
    // projection: tiled-32 A -> f32 row-major out
    proj_kernel<<<GB, 256, 0, stream>>>(xbuf, WT + 2 * 65536, bp, out);
}